// Round 10
// baseline (140.429 us; speedup 1.0000x reference)
//
#include <hip/hip_runtime.h>
#include <stdint.h>

#define IN_F 4096
#define OUT_F 4096
#define M_ROWS 4096   // B*S
#define BM 256
#define BN 128
#define BK 64
#define LDA_B (BM * BK * 2)        // 32 KiB
#define LDB_B (BN * BK * 2)        // 16 KiB

typedef __attribute__((ext_vector_type(8))) short bf16x8;
typedef __attribute__((ext_vector_type(4))) float f32x4;
typedef __attribute__((ext_vector_type(4))) float f4;
typedef __attribute__((ext_vector_type(8))) unsigned short u16x8;

__device__ __forceinline__ unsigned short f32_to_bf16_rne(float f) {
    uint32_t u = __float_as_uint(f);
    u += 0x7FFFu + ((u >> 16) & 1u);
    return (unsigned short)(u >> 16);
}

// ---- merged prepass: x fp32->bf16 (blocks [0,8192)), W expand (blocks [8192,16384)) ----
__global__ __launch_bounds__(256) void prep_kernel(const float* __restrict__ x,
                                                   const float* __restrict__ wsrc,
                                                   unsigned short* __restrict__ xb,
                                                   unsigned short* __restrict__ wb) {
    int b = blockIdx.x;
    if (b < 8192) {
        size_t g = (size_t)b * 256 + threadIdx.x;   // one per 8 elems
        const f4* xp = (const f4*)x + g * 2;
        f4 a = xp[0], c = xp[1];
        u16x8 r;
        r[0] = f32_to_bf16_rne(a[0]); r[1] = f32_to_bf16_rne(a[1]);
        r[2] = f32_to_bf16_rne(a[2]); r[3] = f32_to_bf16_rne(a[3]);
        r[4] = f32_to_bf16_rne(c[0]); r[5] = f32_to_bf16_rne(c[1]);
        r[6] = f32_to_bf16_rne(c[2]); r[7] = f32_to_bf16_rne(c[3]);
        *((u16x8*)xb + g) = r;
    } else {
        size_t g = (size_t)(b - 8192) * 256 + threadIdx.x;
        int o  = (int)(g >> 9);
        int i0 = ((int)g & 511) << 3;
        int bs = (o >> 7) << 7;            // GEMM never reads i < 128-aligned block start
        if (i0 >= bs) {
            int off = o * IN_F - ((o * (o - 1)) >> 1);
            u16x8 r;
#pragma unroll
            for (int j = 0; j < 8; ++j) {
                int i = i0 + j;
                float v = (i >= o) ? wsrc[off + (i - o)] : 0.0f;
                r[j] = f32_to_bf16_rne(v);
            }
            *((u16x8*)wb + g) = r;
        }
    }
}

// ---- A staging: 8-row x 128B unit via global_load_lds; dest linear, source pre-swizzled ----
// LDS row layout: [row][8 slots x 16B], byte(row,slot) = row*128 + (slot ^ (row&7))*16
__device__ __forceinline__ void stage16(const unsigned short* __restrict__ G,
                                        char* lds_dst, int gr0, int k0, int lane) {
    const int lrow  = lane >> 3;                 // 0..7
    const int gslot = (lane & 7) ^ lrow;         // pre-swizzled source slot
    const unsigned short* src = G + (size_t)(gr0 + lrow) * IN_F + k0 + gslot * 8;
    __builtin_amdgcn_global_load_lds(
        (const __attribute__((address_space(1))) void*)src,
        (__attribute__((address_space(3))) void*)lds_dst, 16, 0, 0);
}

__device__ __forceinline__ void stageA(const unsigned short* __restrict__ A,
                                       char* bufA, int m_base, int k0,
                                       int wid, int lane) {
#pragma unroll
    for (int q = 0; q < 4; ++q) {                // A: 32 rows per wave
        const int r0 = q * 64 + wid * 8;
        stage16(A, bufA + r0 * 128, m_base + r0, k0, lane);
    }
}

// ---- B reg-staging: same per-lane source addressing as stage16, result kept in VGPRs ----
__device__ __forceinline__ void loadB(const unsigned short* __restrict__ W,
                                      bf16x8 (&reg)[2], int n_base, int k0,
                                      int wid, int lane) {
    const int lrow  = lane >> 3;
    const int gslot = (lane & 7) ^ lrow;
#pragma unroll
    for (int q = 0; q < 2; ++q) {
        const int row = q * 64 + wid * 8 + lrow;
        reg[q] = *(const bf16x8*)(W + (size_t)(n_base + row) * IN_F + k0 + gslot * 8);
    }
}

// ds_write to the SAME linear dest global_load_lds would use -> identical LDS layout
__device__ __forceinline__ void writeB(char* bufB, bf16x8 (&reg)[2], int wid, int lane) {
#pragma unroll
    for (int q = 0; q < 2; ++q) {
        const int r0 = q * 64 + wid * 8;
        *(bf16x8*)(bufB + r0 * 128 + lane * 16) = reg[q];
    }
}

__device__ __forceinline__ const bf16x8* lds_frag(const char* buf, int row, int slot) {
    return (const bf16x8*)(buf + row * 128 + ((slot ^ (row & 7)) * 16));
}

// ---- main GEMM: C[m][n] = sum_{k>=n_base} A[m][k]*W[n][k] + bias[n] ----
// R2's proven depth-3 structure; A via DMA path, B via load-return + ds_write path.
__global__ __launch_bounds__(512, 2) void tri_gemm_kernel(const unsigned short* __restrict__ A,
                                                          const unsigned short* __restrict__ W,
                                                          const float* __restrict__ bias,
                                                          float* __restrict__ C) {
    __shared__ __align__(16) char smem[3 * LDA_B + 3 * LDB_B];   // 144 KiB

    const int u = blockIdx.x;
    const int tile_n = u >> 4;          // desc-K order -> greedy LPT, 66 K-tiles/CU uniform
    const int tile_m = u & 15;
    const int m_base = tile_m * BM;
    const int n_base = tile_n * BN;
    const int nt = (IN_F - n_base) / BK;   // 64 - 2*tile_n, even, min 2

    const int tid  = threadIdx.x;
    const int wid  = tid >> 6;
    const int lane = tid & 63;
    const int wr = wid >> 1;            // 0..3  (64-row band)
    const int wc = wid & 1;             // 0..1  (64-col band)
    const int frow  = lane & 15;
    const int khalf = lane >> 4;

    char* a0 = smem;               char* a1 = smem + LDA_B;        char* a2 = smem + 2 * LDA_B;
    char* b0 = smem + 3 * LDA_B;   char* b1 = b0 + LDB_B;          char* b2 = b0 + 2 * LDB_B;

    f32x4 acc[4][4];
#pragma unroll
    for (int i = 0; i < 4; ++i)
#pragma unroll
        for (int j = 0; j < 4; ++j) acc[i][j] = (f32x4){0.f, 0.f, 0.f, 0.f};

    bf16x8 regE[2], regO[2];    // B-reg double buffer (static parity via x2 unroll)

    // prologue: tiles 0,1: A via DMA, B to regs; B(0) written to LDS
    stageA(A, a0, m_base, n_base, wid, lane);
    loadB(W, regE, n_base, n_base, wid, lane);
    stageA(A, a1, m_base, n_base + BK, wid, lane);
    loadB(W, regO, n_base, n_base + BK, wid, lane);
    asm volatile("s_waitcnt vmcnt(6)" ::: "memory");   // A(0)+B(0) done; A(1)+B(1) in flight
    writeB(b0, regE, wid, lane);
    asm volatile("s_waitcnt lgkmcnt(0)" ::: "memory");

    // iter invariant (entry): LDS has tiles t (a0,b0 published to all waves after the
    // barrier); in flight: A(t+1) DMA (4 ops) + B(t+1) in regHold's loads (2 ops).
    auto iter = [&](int t, bf16x8 (&regW)[2], bf16x8 (&regHold)[2]) {
        if (t + 1 < nt) { asm volatile("s_waitcnt vmcnt(6)" ::: "memory"); }
        else            { asm volatile("s_waitcnt vmcnt(0)" ::: "memory"); }
        __builtin_amdgcn_sched_barrier(0);
        __builtin_amdgcn_s_barrier();      // tile t published (A drained + B written in iter t-1)
        __builtin_amdgcn_sched_barrier(0);

        if (t + 2 < nt) {
            stageA(A, a2, m_base, n_base + (t + 2) * BK, wid, lane);
            loadB(W, regW, n_base, n_base + (t + 2) * BK, wid, lane);
            asm volatile("s_waitcnt vmcnt(6)" ::: "memory");   // drain A(t+1) DMA + B(t+1) regs
        } else {
            asm volatile("s_waitcnt vmcnt(0)" ::: "memory");
        }
        if (t + 1 < nt) writeB(b1, regHold, wid, lane);        // B(t+1) -> next buffer

        const char* bufA = a0;
        const char* bufB = b0;
#pragma unroll
        for (int ks = 0; ks < 2; ++ks) {
            bf16x8 af[4], bfr[4];
#pragma unroll
            for (int i = 0; i < 4; ++i)
                af[i] = *lds_frag(bufA, wr * 64 + i * 16 + frow, ks * 4 + khalf);
#pragma unroll
            for (int j = 0; j < 4; ++j)
                bfr[j] = *lds_frag(bufB, wc * 64 + j * 16 + frow, ks * 4 + khalf);
            __builtin_amdgcn_s_setprio(1);
#pragma unroll
            for (int i = 0; i < 4; ++i)
#pragma unroll
                for (int j = 0; j < 4; ++j)
                    acc[i][j] = __builtin_amdgcn_mfma_f32_16x16x32_bf16(af[i], bfr[j], acc[i][j], 0, 0, 0);
            __builtin_amdgcn_s_setprio(0);
        }

        asm volatile("s_waitcnt lgkmcnt(0)" ::: "memory");   // reads+writes retired
        __builtin_amdgcn_sched_barrier(0);

        char* ta = a0; a0 = a1; a1 = a2; a2 = ta;   // rotate roles
        char* tb = b0; b0 = b1; b1 = b2; b2 = tb;
    };

    for (int t = 0; t < nt; t += 2) {   // nt always even
        iter(t, regE, regO);
        iter(t + 1, regO, regE);
    }

    // ---- epilogue: D layout col=lane&15, row=(lane>>4)*4+q ----
    const int col0 = n_base + wc * 64;
    const int row0 = m_base + wr * 64;
#pragma unroll
    for (int nj = 0; nj < 4; ++nj) {
        const int col = col0 + nj * 16 + frow;
        const float bv = bias[col];
#pragma unroll
        for (int mi = 0; mi < 4; ++mi) {
            const int rbase = row0 + mi * 16 + khalf * 4;
#pragma unroll
            for (int q = 0; q < 4; ++q) {
                C[(size_t)(rbase + q) * OUT_F + col] = acc[mi][nj][q] + bv;
            }
        }
    }
}

extern "C" void kernel_launch(void* const* d_in, const int* in_sizes, int n_in,
                              void* d_out, int out_size, void* d_ws, size_t ws_size,
                              hipStream_t stream) {
    const float* x    = (const float*)d_in[0];
    const float* w    = (const float*)d_in[1];
    const float* bias = (const float*)d_in[2];
    float* out = (float*)d_out;

    unsigned short* xb = (unsigned short*)d_ws;                  // 32 MiB bf16 x
    unsigned short* wb = xb + (size_t)M_ROWS * IN_F;             // 32 MiB bf16 dense W

    prep_kernel<<<16384, 256, 0, stream>>>(x, w, xb, wb);
    tri_gemm_kernel<<<512, 512, 0, stream>>>(xb, wb, bias, out);
}